// Round 2
// baseline (26.208 us; speedup 1.0000x reference)
//
#include <hip/hip_runtime.h>
#include <math.h>

// Problem constants (match reference setup_inputs)
#define BB 32
#define LL 1024
#define PP 8
#define DD 256
#define MARGIN_F 0.01f
// total = B * P * (L - P) = 32 * 8 * 1016
#define TOTAL_PAIRS 260096.0f

// Kernel 1: sim[b,l] = cos(sent[b,l,:], query[b,:])
// 16 lanes per row, each lane accumulates 16 floats (4x float4, coalesced:
// for each k, the 16 lanes of a row-group read a contiguous 256B segment).
// Reduction: 4 shfl_xor levels within the 16-lane group (3 vars -> 12 shfl
// per wave for 4 rows, vs 18/row in the 64-lane-per-row version).
__global__ __launch_bounds__(256) void sim_kernel(const float* __restrict__ sent,
                                                  const float* __restrict__ query,
                                                  float* __restrict__ sim) {
    const int tid = threadIdx.x;
    const int row = blockIdx.x * 16 + (tid >> 4);  // 16 rows per block
    const int seg = tid & 15;
    const int b   = row >> 10;                     // L = 1024

    const float* xr = sent  + (size_t)row * DD;
    const float* qr = query + (size_t)b   * DD;

    float dot = 0.f, nx = 0.f, nq = 0.f;
#pragma unroll
    for (int k = 0; k < 4; ++k) {
        const int off = (k * 16 + seg) * 4;
        const float4 x = *reinterpret_cast<const float4*>(xr + off);
        const float4 q = *reinterpret_cast<const float4*>(qr + off);
        dot += x.x * q.x + x.y * q.y + x.z * q.z + x.w * q.w;
        nx  += x.x * x.x + x.y * x.y + x.z * x.z + x.w * x.w;
        nq  += q.x * q.x + q.y * q.y + q.z * q.z + q.w * q.w;
    }

#pragma unroll
    for (int off = 8; off > 0; off >>= 1) {
        dot += __shfl_xor(dot, off, 64);
        nx  += __shfl_xor(nx,  off, 64);
        nq  += __shfl_xor(nq,  off, 64);
    }
    if (seg == 0) {
        const float den = fmaxf(sqrtf(nx), 1e-12f) * fmaxf(sqrtf(nq), 1e-12f);
        sim[row] = dot / den;
    }
}

// Kernel 2 (fused loss + finalize): single block, 1024 threads.
// 32 threads per split scan that split's 1024 sims (all L2-resident),
// accumulate the pairwise hinge against the 8 staged positive sims,
// block-reduce, scale, write out[0]. Deterministic reduction tree.
__global__ __launch_bounds__(1024) void loss_kernel(const float* __restrict__ sim,
                                                    const int* __restrict__ pos_idx,
                                                    float* __restrict__ out) {
    const int tid = threadIdx.x;

    __shared__ float sp[BB * PP];   // positive sims
    __shared__ int   pidx[BB * PP]; // positive indices
    if (tid < BB * PP) {
        const int b = tid >> 3;
        const int idx = pos_idx[tid];
        pidx[tid] = idx;
        sp[tid]   = sim[b * LL + idx];
    }
    __syncthreads();

    const int b   = tid >> 5;   // 32 threads per split
    const int sub = tid & 31;

    float acc = 0.0f;
#pragma unroll
    for (int it = 0; it < LL / 32; ++it) {
        const int l = sub + it * 32;
        const float s = sim[b * LL + l];
        bool is_pos = false;
#pragma unroll
        for (int p = 0; p < PP; ++p) is_pos |= (l == pidx[b * PP + p]);
        if (!is_pos) {
#pragma unroll
            for (int p = 0; p < PP; ++p)
                acc += fmaxf(s - sp[b * PP + p] + MARGIN_F, 0.0f);
        }
    }

    // wave reduce, then cross-wave (16 waves) via LDS, thread 0 finishes.
#pragma unroll
    for (int off = 32; off > 0; off >>= 1) acc += __shfl_xor(acc, off, 64);

    __shared__ float wsum[16];
    if ((tid & 63) == 0) wsum[tid >> 6] = acc;
    __syncthreads();
    if (tid == 0) {
        float total = 0.0f;
#pragma unroll
        for (int w = 0; w < 16; ++w) total += wsum[w];
        out[0] = total / TOTAL_PAIRS;  // WRITE (no accumulation across replays)
    }
}

extern "C" void kernel_launch(void* const* d_in, const int* in_sizes, int n_in,
                              void* d_out, int out_size, void* d_ws, size_t ws_size,
                              hipStream_t stream) {
    const float* sent  = (const float*)d_in[0];   // [B, L, D] f32
    const float* query = (const float*)d_in[1];   // [B, D]    f32
    const int*   pidx  = (const int*)d_in[2];     // [B, P]
    float* out = (float*)d_out;

    float* sim = (float*)d_ws;                    // B*L floats = 128 KiB

    sim_kernel<<<(BB * LL) / 16, 256, 0, stream>>>(sent, query, sim);
    loss_kernel<<<1, 1024, 0, stream>>>(sim, pidx, out);
}